// Round 5
// baseline (105.777 us; speedup 1.0000x reference)
//
#include <hip/hip_runtime.h>
#include <hip/hip_bf16.h>

// RDF with minimum-image PBC + Gaussian smearing, N=2048 atoms, 100 bins.
//
// Round-5: single fused dispatch. Hot pair loop does ONE LDS atomicAdd(1.0f)
// into a FINE distance histogram (S=17 sub-bins/coarse bin; integer counts in
// f32 -> exact, order-independent). Per-block epilogue convolves with a
// 103-tap Gaussian table (stride 17 coprime with 32 banks -> conflict-free).
// Pairs with dist < 8 bin-units (~200 device-wide) take an EXACT direct-smear
// path into coarse bins 0..11 (tiny-shell-volume rdf normalization amplifies
// quantization error there). Blocks publish a 100-bin partial (transposed
// [bin][block]), __threadfence(), take a ticket; the LAST block reduces the
// partials (float4, fixed order -> deterministic), normalizes, and writes
// d_out = [count(100) | bins(101) | rdf(100)]. Ticket is zeroed by a 4-byte
// hipMemsetAsync node (graph-capture legal).

#define N_ATOMS 2048
#define HALF    1024
#define NBINS   100
#define S_FINE  17          // fine sub-bins per coarse bin (coprime with 32)
#define FBINS   1744        // > 102.5 * 17 = 1742.5
#define TAPS    103         // 2*3*17 + 1  (window +-3 bin widths)
#define NDIR    12          // exact direct-path coarse bins 0..11
#define TLOW    8.0f        // bin-units: below this, take the exact path

__global__ __launch_bounds__(512) void rdf_fused(
    const float* __restrict__ xyz,
    const float* __restrict__ cell,
    const float* __restrict__ offsets,
    const float* __restrict__ bins,
    float* __restrict__ out,
    float* __restrict__ partials,
    unsigned* __restrict__ ticket,
    int nblocks)
{
    __shared__ float fine[FBINS];       // fine distance histogram (counts)
    __shared__ float wtab[TAPS];        // Gaussian taps
    __shared__ float conv[NBINS][4];    // conv partials; reused by final reduce
    __shared__ float cd[16];            // exact direct-path coarse bins
    __shared__ float ssum[2];
    __shared__ unsigned stick;

    const int tid = threadIdx.x;

    for (int a = tid; a < FBINS; a += 512) fine[a] = 0.0f;
    if (tid < 16)   cd[tid] = 0.0f;
    if (tid < TAPS) {
        const float u = ((float)tid - 50.5f) * (1.0f / (float)S_FINE);
        wtab[tid] = __expf(-0.5f * u * u);
    }
    __syncthreads();

    const float cx = cell[0], cy = cell[1], cz = cell[2];
    const float hcx = 0.5f * cx, hcy = 0.5f * cy, hcz = 0.5f * cz;

    const float width = offsets[1] - offsets[0];   // 7.5/99
    const float invw  = 1.0f / width;
    // beyond 102.5 bin-units no bin k<=99 lies within the +-3w window
    const float cutd   = 102.5f * width;           // 7.765 < CUTOFF_B = 8.0
    const float cut2   = cutd * cutd;
    const float finesc = invw * (float)S_FINE;     // dist -> fine-bin units

    const int total = N_ATOMS * HALF;              // 2^21 unique-pair slots
    const int gsize = nblocks * 512;

    for (int q = blockIdx.x * 512 + tid; q < total; q += gsize) {
        const int i = q >> 10;
        const int t = q & (HALF - 1);
        if (t == HALF - 1 && i >= HALF) continue;  // dedup d==N/2 diagonal
        const int j = (i + 1 + t) & (N_ATOMS - 1);

        // i-loads wave-uniform (broadcast), j-loads stride-12B coalesced;
        // xyz = 24KB -> L1-resident
        const float xi = xyz[3 * i + 0];
        const float yi = xyz[3 * i + 1];
        const float zi = xyz[3 * i + 2];
        float dx = xyz[3 * j + 0] - xi;
        float dy = xyz[3 * j + 1] - yi;
        float dz = xyz[3 * j + 2] - zi;
        // minimum-image wrap (matches reference shift semantics)
        dx += (dx >= hcx) ? -cx : ((dx < -hcx) ? cx : 0.0f);
        dy += (dy >= hcy) ? -cy : ((dy < -hcy) ? cy : 0.0f);
        dz += (dz >= hcz) ? -cz : ((dz < -hcz) ? cz : 0.0f);

        const float dsq = dx * dx + dy * dy + dz * dz;
        if (dsq < cut2 && dsq != 0.0f) {
            const float tu = sqrtf(dsq) * invw;    // distance in bin units
            if (tu >= TLOW) {
                // ONE atomic/pair; 64 lanes scatter over 1744 bins
                atomicAdd(&fine[(int)(tu * finesc * width)], 1.0f);
            } else {
                // exact path for low bins (~200 pairs device-wide)
                int khi = (int)tu + 4; if (khi > NDIR - 1) khi = NDIR - 1;
                for (int k = 0; k <= khi; ++k) {
                    const float e = tu - (float)k;
                    atomicAdd(&cd[k], __expf(-0.5f * e * e));
                }
            }
        }
    }

    __syncthreads();

    // coarse[k] = sum_d wtab[d+51] * fine[17k+d], d in [-51,51]
    // 400 threads: k = t>>2, chunk c = t&3 (26/26/26/25 taps); stride-17
    // fine reads are bank-conflict free (gcd(17,32)=1)
    if (tid < 400) {
        const int k = tid >> 2;
        const int c = tid & 3;
        const int m0 = c * 26;
        const int mcnt = (c == 3) ? 25 : 26;
        float s = 0.0f;
        for (int mm = 0; mm < mcnt; ++mm) {
            const int m = m0 + mm;
            const int f = S_FINE * k + m - 51;     // max 17*99+51 = 1734
            if (f >= 0) s += wtab[m] * fine[f];
        }
        conv[k][c] = s;
    }
    __syncthreads();

    if (tid < NBINS) {
        float raw = conv[tid][0] + conv[tid][1] + conv[tid][2] + conv[tid][3];
        if (tid < NDIR) raw += cd[tid];
        partials[tid * nblocks + blockIdx.x] = raw;   // transposed
    }

    // ---- last-block reduction (non-spinning: no co-residency needed) ----
    __threadfence();                                   // release partials
    if (tid == 0) stick = atomicAdd(ticket, 1u);
    __syncthreads();
    if (stick != (unsigned)(nblocks - 1)) return;
    __threadfence();                                   // acquire partials

    // reduce: 400 threads, bin b = t>>2, chunk c = t&3, nblocks/4 floats each
    if (tid < 400) {
        const int b = tid >> 2;
        const int c = tid & 3;
        const int chunk = nblocks >> 2;                // multiple of 8
        const float4* src = (const float4*)(partials + b * nblocks + c * chunk);
        const int n4 = chunk >> 2;
        float s0 = 0.0f, s1 = 0.0f;
        #pragma unroll 8
        for (int q2 = 0; q2 + 1 < n4; q2 += 2) {
            const float4 v0 = src[q2];
            const float4 v1 = src[q2 + 1];
            s0 += v0.x + v0.y + v0.z + v0.w;
            s1 += v1.x + v1.y + v1.z + v1.w;
        }
        conv[b][c] = s0 + s1;
    }
    __syncthreads();

    float raw = 0.0f;
    if (tid < NBINS) {
        raw = conv[tid][0] + conv[tid][1] + conv[tid][2] + conv[tid][3];
    }
    if (tid < 128) {
        float v = raw;
        #pragma unroll
        for (int o = 32; o > 0; o >>= 1) v += __shfl_down(v, o);
        if ((tid & 63) == 0) ssum[tid >> 6] = v;
    }
    __syncthreads();
    const float S = ssum[0] + ssum[1];

    if (tid < NBINS) {
        const float cnt = raw / S;
        out[tid] = cnt;                                // count
        const float b0 = bins[tid], b1 = bins[tid + 1];
        const float R  = bins[NBINS];                  // R_END = 7.5
        // rdf = cnt / (vol_bin / V) = cnt * R^3 / (b1^3 - b0^3)  (4pi/3 cancels)
        out[201 + tid] = cnt * (R * R * R) / (b1 * b1 * b1 - b0 * b0 * b0);
    }
    if (tid < NBINS + 1) {
        out[100 + tid] = bins[tid];                    // bins passthrough
    }
}

extern "C" void kernel_launch(void* const* d_in, const int* in_sizes, int n_in,
                              void* d_out, int out_size, void* d_ws, size_t ws_size,
                              hipStream_t stream) {
    const float* xyz     = (const float*)d_in[0];
    const float* cell    = (const float*)d_in[1];
    const float* bins    = (const float*)d_in[2];
    const float* offsets = (const float*)d_in[3];
    float* out = (float*)d_out;

    int nblocks = 512;                  // 2 blocks/CU x 8 waves = 16 waves/CU
    const int maxblocks = (int)((ws_size - 4) / (NBINS * sizeof(float)));
    if (nblocks > maxblocks) nblocks = maxblocks;
    nblocks &= ~31;                     // chunk = nblocks/4 stays float4-aligned
    if (nblocks < 32) nblocks = 32;

    float*    partials = (float*)d_ws;
    unsigned* ticket   = (unsigned*)((char*)d_ws + (size_t)NBINS * nblocks * sizeof(float));

    hipMemsetAsync(ticket, 0, sizeof(unsigned), stream);
    rdf_fused<<<nblocks, 512, 0, stream>>>(xyz, cell, offsets, bins, out,
                                           partials, ticket, nblocks);
}

// Round 6
// 33.568 us; speedup vs baseline: 3.1511x; 3.1511x over previous
//
#include <hip/hip_runtime.h>
#include <hip/hip_bf16.h>

// RDF with minimum-image PBC + Gaussian smearing, N=2048 atoms, 100 bins.
//
// Round-6: single fused dispatch, FENCE-FREE cross-block reduction.
// Round 5's __threadfence() per block forced per-XCD L2 writebacks
// (~100us serialized). Instead: blocks atomicAdd their 100-bin partial
// directly into global acc[] (device-scope atomics are coherent across
// XCDs in hardware — no fence), __syncthreads() drains each wave's
// outstanding atomics (compiler emits s_waitcnt vmcnt(0) before
// s_barrier), then thread 0 takes a RELAXED ticket. The last block reads
// acc back with atomicAdd(p, 0.0f) — an RMW at the coherence point, so
// visibility needs no acquire fence — normalizes, and writes
// d_out = [count(100) | bins(101) | rdf(100)].
//
// Hot loop (unchanged from round 4): ONE LDS atomicAdd(1.0f) per pair into
// a FINE distance histogram (17 sub-bins/bin; integer counts in f32 ->
// exact); per-block epilogue convolves with a 103-tap Gaussian (stride 17
// coprime with 32 banks -> conflict-free). Pairs with dist < 8 bin-units
// take an exact direct-smear path into bins 0..11 (tiny shell volumes
// amplify quantization error there). Ticket+acc zeroed by a 404-byte
// hipMemsetAsync node (graph-capture legal).

#define N_ATOMS 2048
#define HALF    1024
#define NBINS   100
#define S_FINE  17          // fine sub-bins per coarse bin (coprime with 32)
#define FBINS   1744        // > 102.5 * 17 = 1742.5
#define TAPS    103         // 2*3*17 + 1  (window +-3 bin widths)
#define NDIR    12          // exact direct-path coarse bins 0..11
#define TLOW    8.0f        // bin-units: below this, take the exact path

__global__ __launch_bounds__(512) void rdf_fused(
    const float* __restrict__ xyz,
    const float* __restrict__ cell,
    const float* __restrict__ offsets,
    const float* __restrict__ bins,
    float* __restrict__ out,
    float* __restrict__ acc,        // [NBINS] global accumulator (pre-zeroed)
    unsigned* __restrict__ ticket,  // pre-zeroed
    int nblocks)
{
    __shared__ float fine[FBINS];       // fine distance histogram (counts)
    __shared__ float wtab[TAPS];        // Gaussian taps
    __shared__ float conv[NBINS][4];    // per-chunk convolution partials
    __shared__ float cd[16];            // exact direct-path coarse bins
    __shared__ float ssum[2];
    __shared__ unsigned stick;

    const int tid = threadIdx.x;

    for (int a = tid; a < FBINS; a += 512) fine[a] = 0.0f;
    if (tid < 16)   cd[tid] = 0.0f;
    if (tid < TAPS) {
        const float u = ((float)tid - 50.5f) * (1.0f / (float)S_FINE);
        wtab[tid] = __expf(-0.5f * u * u);
    }
    __syncthreads();

    const float cx = cell[0], cy = cell[1], cz = cell[2];
    const float hcx = 0.5f * cx, hcy = 0.5f * cy, hcz = 0.5f * cz;

    const float width = offsets[1] - offsets[0];   // 7.5/99
    const float invw  = 1.0f / width;
    // beyond 102.5 bin-units no bin k<=99 lies within the +-3w window
    const float cutd   = 102.5f * width;           // 7.765 < CUTOFF_B = 8.0
    const float cut2   = cutd * cutd;

    const int total = N_ATOMS * HALF;              // 2^21 unique-pair slots
    const int gsize = nblocks * 512;

    for (int q = blockIdx.x * 512 + tid; q < total; q += gsize) {
        const int i = q >> 10;
        const int t = q & (HALF - 1);
        if (t == HALF - 1 && i >= HALF) continue;  // dedup d==N/2 diagonal
        const int j = (i + 1 + t) & (N_ATOMS - 1);

        // i-loads near-uniform (L1 broadcast), j-loads stride-12B coalesced;
        // xyz = 24KB -> L1-resident
        const float xi = xyz[3 * i + 0];
        const float yi = xyz[3 * i + 1];
        const float zi = xyz[3 * i + 2];
        float dx = xyz[3 * j + 0] - xi;
        float dy = xyz[3 * j + 1] - yi;
        float dz = xyz[3 * j + 2] - zi;
        // minimum-image wrap (matches reference shift semantics)
        dx += (dx >= hcx) ? -cx : ((dx < -hcx) ? cx : 0.0f);
        dy += (dy >= hcy) ? -cy : ((dy < -hcy) ? cy : 0.0f);
        dz += (dz >= hcz) ? -cz : ((dz < -hcz) ? cz : 0.0f);

        const float dsq = dx * dx + dy * dy + dz * dz;
        if (dsq < cut2 && dsq != 0.0f) {
            const float tu = sqrtf(dsq) * invw;    // distance in bin units
            if (tu >= TLOW) {
                // ONE LDS atomic/pair; 64 lanes scatter over 1744 bins
                atomicAdd(&fine[(int)(tu * (float)S_FINE)], 1.0f);
            } else {
                // exact path for low bins (~200 pairs device-wide)
                int khi = (int)tu + 4; if (khi > NDIR - 1) khi = NDIR - 1;
                for (int k = 0; k <= khi; ++k) {
                    const float e = tu - (float)k;
                    atomicAdd(&cd[k], __expf(-0.5f * e * e));
                }
            }
        }
    }

    __syncthreads();

    // coarse[k] = sum_d wtab[d+51] * fine[17k+d], d in [-51,51]
    // 400 threads: k = t>>2, chunk c = t&3 (26/26/26/25 taps); stride-17
    // fine reads are bank-conflict free (gcd(17,32)=1)
    if (tid < 400) {
        const int k = tid >> 2;
        const int c = tid & 3;
        const int m0 = c * 26;
        const int mcnt = (c == 3) ? 25 : 26;
        float s = 0.0f;
        for (int mm = 0; mm < mcnt; ++mm) {
            const int m = m0 + mm;
            const int f = S_FINE * k + m - 51;     // max 17*99+51 = 1734
            if (f >= 0) s += wtab[m] * fine[f];
        }
        conv[k][c] = s;
    }
    __syncthreads();

    // publish: device-scope atomic adds into global acc (no fence needed)
    if (tid < NBINS) {
        float raw = conv[tid][0] + conv[tid][1] + conv[tid][2] + conv[tid][3];
        if (tid < NDIR) raw += cd[tid];
        atomicAdd(&acc[tid], raw);
    }

    // barrier drains each wave's outstanding vmem (incl. the atomics) before
    // any thread proceeds -> ticket increment happens-after our adds complete
    __syncthreads();
    if (tid == 0) stick = atomicAdd(ticket, 1u);   // relaxed, no fence
    __syncthreads();
    if (stick != (unsigned)(nblocks - 1)) return;

    // ---- last block: all other blocks' adds have completed ----
    float raw = 0.0f;
    if (tid < NBINS) {
        raw = atomicAdd(&acc[tid], 0.0f);          // RMW read at coherence point
    }
    if (tid < 128) {
        float v = raw;
        #pragma unroll
        for (int o = 32; o > 0; o >>= 1) v += __shfl_down(v, o);
        if ((tid & 63) == 0) ssum[tid >> 6] = v;
    }
    __syncthreads();
    const float S = ssum[0] + ssum[1];

    if (tid < NBINS) {
        const float cnt = raw / S;
        out[tid] = cnt;                                // count
        const float b0 = bins[tid], b1 = bins[tid + 1];
        const float R  = bins[NBINS];                  // R_END = 7.5
        // rdf = cnt / (vol_bin / V) = cnt * R^3 / (b1^3 - b0^3)  (4pi/3 cancels)
        out[201 + tid] = cnt * (R * R * R) / (b1 * b1 * b1 - b0 * b0 * b0);
    }
    if (tid < NBINS + 1) {
        out[100 + tid] = bins[tid];                    // bins passthrough
    }
}

extern "C" void kernel_launch(void* const* d_in, const int* in_sizes, int n_in,
                              void* d_out, int out_size, void* d_ws, size_t ws_size,
                              hipStream_t stream) {
    const float* xyz     = (const float*)d_in[0];
    const float* cell    = (const float*)d_in[1];
    const float* bins    = (const float*)d_in[2];
    const float* offsets = (const float*)d_in[3];
    float* out = (float*)d_out;

    float*    acc    = (float*)d_ws;                          // 100 floats
    unsigned* ticket = (unsigned*)((char*)d_ws + NBINS * sizeof(float));

    const int nblocks = 512;   // 2 blocks/CU x 8 waves = 16 waves/CU

    // zero acc + ticket each call (graph-capture legal async memset)
    hipMemsetAsync(d_ws, 0, NBINS * sizeof(float) + sizeof(unsigned), stream);
    rdf_fused<<<nblocks, 512, 0, stream>>>(xyz, cell, offsets, bins, out,
                                           acc, ticket, nblocks);
}

// Round 7
// 24.656 us; speedup vs baseline: 4.2902x; 1.3615x over previous
//
#include <hip/hip_runtime.h>
#include <hip/hip_bf16.h>

// RDF with minimum-image PBC + Gaussian smearing, N=2048 atoms, 100 bins.
//
// Round-7: single fused dispatch with STRIPED fence-free publish.
// Round 6's regression was same-address atomic contention: 512 blocks
// atomicAdd'ing the same 100 acc words = 512 serialized coherence-point
// RMWs per address (~20us). Now acc[16][100]: block publishes into stripe
// (blockIdx & 15) -> 32 adds/address (~1.3us, overlapped). Last-ticket
// block reads the 1600 stripe values back with atomicAdd(p,0.0f) RMWs
// (coherence-point reads, no fence needed), reduces, normalizes, writes
// d_out = [count(100) | bins(101) | rdf(100)].
//
// Main loop: block b owns rows 4b..4b+3 of the cyclic upper-triangle
// enumeration (j = (i+1+t) mod N, t in [0,1024); one predicate dedups the
// d==N/2 diagonal; the x2 pair weight cancels in normalization). i is
// wave-uniform -> i-coordinate loads are scalar; j-loads stride-12B
// coalesced, L1-resident (xyz = 24KB). ONE LDS atomicAdd(1.0f) per pair
// into a FINE distance histogram (17 sub-bins/bin; integer counts in f32
// -> exact, order-independent); per-block epilogue convolves with a
// 103-tap Gaussian (stride 17 coprime with 32 banks -> conflict-free).
// Pairs with dist < 8 bin-units take an exact direct-smear path into bins
// 0..11 (tiny shell volumes amplify quantization error there).
// acc+ticket zeroed by one 6404-byte hipMemsetAsync node (capture-legal).

#define N_ATOMS 2048
#define HALF    1024
#define NBINS   100
#define S_FINE  17          // fine sub-bins per coarse bin (coprime with 32)
#define FBINS   1744        // > 102.5 * 17 = 1742.5
#define TAPS    103         // 2*3*17 + 1  (window +-3 bin widths)
#define NDIR    12          // exact direct-path coarse bins 0..11
#define TLOW    8.0f        // bin-units: below this, take the exact path
#define STRIPES 16
#define NBLOCKS 512
#define ROWS_PB 4           // N_ATOMS / NBLOCKS

__global__ __launch_bounds__(512) void rdf_fused(
    const float* __restrict__ xyz,
    const float* __restrict__ cell,
    const float* __restrict__ offsets,
    const float* __restrict__ bins,
    float* __restrict__ out,
    float* __restrict__ acc,        // [STRIPES][NBINS], pre-zeroed
    unsigned* __restrict__ ticket)  // pre-zeroed
{
    __shared__ float fine[FBINS];       // fine distance histogram (counts)
    __shared__ float wtab[TAPS];        // Gaussian taps
    __shared__ float conv[NBINS][4];    // conv partials; reused by tail reduce
    __shared__ float cd[16];            // exact direct-path coarse bins
    __shared__ float ssum[2];
    __shared__ unsigned stick;

    const int tid = threadIdx.x;

    for (int a = tid; a < FBINS; a += 512) fine[a] = 0.0f;
    if (tid < 16)   cd[tid] = 0.0f;
    if (tid < TAPS) {
        const float u = ((float)tid - 50.5f) * (1.0f / (float)S_FINE);
        wtab[tid] = __expf(-0.5f * u * u);
    }
    __syncthreads();

    const float cx = cell[0], cy = cell[1], cz = cell[2];
    const float hcx = 0.5f * cx, hcy = 0.5f * cy, hcz = 0.5f * cz;

    const float width = offsets[1] - offsets[0];   // 7.5/99
    const float invw  = 1.0f / width;
    // beyond 102.5 bin-units no bin k<=99 lies within the +-3w window
    const float cutd   = 102.5f * width;           // 7.765 < CUTOFF_B = 8.0
    const float cut2   = cutd * cutd;

    // ---- main loop: 4 rows per block, i wave-uniform ----
    const int row0 = blockIdx.x << 2;
    #pragma unroll
    for (int r = 0; r < ROWS_PB; ++r) {
        const int i = row0 + r;
        const float xi = xyz[3 * i + 0];           // uniform -> scalar loads
        const float yi = xyz[3 * i + 1];
        const float zi = xyz[3 * i + 2];
        #pragma unroll
        for (int th = tid; th < HALF; th += 512) {
            if (th == HALF - 1 && i >= HALF) continue;   // dedup N/2 diagonal
            const int j = (i + 1 + th) & (N_ATOMS - 1);

            float dx = xyz[3 * j + 0] - xi;
            float dy = xyz[3 * j + 1] - yi;
            float dz = xyz[3 * j + 2] - zi;
            // minimum-image wrap (matches reference shift semantics)
            dx += (dx >= hcx) ? -cx : ((dx < -hcx) ? cx : 0.0f);
            dy += (dy >= hcy) ? -cy : ((dy < -hcy) ? cy : 0.0f);
            dz += (dz >= hcz) ? -cz : ((dz < -hcz) ? cz : 0.0f);

            const float dsq = dx * dx + dy * dy + dz * dz;
            if (dsq < cut2 && dsq != 0.0f) {
                const float tu = sqrtf(dsq) * invw;    // dist in bin units
                if (tu >= TLOW) {
                    // ONE LDS atomic/pair; lanes scatter over 1744 bins
                    atomicAdd(&fine[(int)(tu * (float)S_FINE)], 1.0f);
                } else {
                    // exact path for low bins (~200 pairs device-wide)
                    int khi = (int)tu + 4; if (khi > NDIR - 1) khi = NDIR - 1;
                    for (int k = 0; k <= khi; ++k) {
                        const float e = tu - (float)k;
                        atomicAdd(&cd[k], __expf(-0.5f * e * e));
                    }
                }
            }
        }
    }

    __syncthreads();

    // coarse[k] = sum_d wtab[d+51] * fine[17k+d], d in [-51,51]
    // 400 threads: k = t>>2, chunk c = t&3 (26/26/26/25 taps); stride-17
    // fine reads are bank-conflict free (gcd(17,32)=1)
    if (tid < 400) {
        const int k = tid >> 2;
        const int c = tid & 3;
        const int m0 = c * 26;
        const int mcnt = (c == 3) ? 25 : 26;
        float s = 0.0f;
        for (int mm = 0; mm < mcnt; ++mm) {
            const int m = m0 + mm;
            const int f = S_FINE * k + m - 51;     // max 17*99+51 = 1734
            if (f >= 0) s += wtab[m] * fine[f];
        }
        conv[k][c] = s;
    }
    __syncthreads();

    // striped publish: 32 blocks per stripe -> low same-address contention
    if (tid < NBINS) {
        float raw = conv[tid][0] + conv[tid][1] + conv[tid][2] + conv[tid][3];
        if (tid < NDIR) raw += cd[tid];
        atomicAdd(&acc[(blockIdx.x & (STRIPES - 1)) * NBINS + tid], raw);
    }

    // barrier drains each wave's outstanding vmem (incl. atomics) before
    // the ticket increment -> increment happens-after our adds complete
    __syncthreads();
    if (tid == 0) stick = atomicAdd(ticket, 1u);   // relaxed, no fence
    __syncthreads();
    if (stick != (unsigned)(NBLOCKS - 1)) return;

    // ---- last block: all other blocks' adds have completed ----
    // read stripes via RMW at the coherence point (no acquire fence needed)
    if (tid < 400) {
        const int b = tid >> 2;
        const int c = tid & 3;
        float s = 0.0f;
        #pragma unroll
        for (int k = 0; k < 4; ++k) {
            s += atomicAdd(&acc[(c * 4 + k) * NBINS + b], 0.0f);
        }
        conv[b][c] = s;
    }
    __syncthreads();

    float raw = 0.0f;
    if (tid < NBINS) {
        raw = conv[tid][0] + conv[tid][1] + conv[tid][2] + conv[tid][3];
    }
    if (tid < 128) {
        float v = raw;
        #pragma unroll
        for (int o = 32; o > 0; o >>= 1) v += __shfl_down(v, o);
        if ((tid & 63) == 0) ssum[tid >> 6] = v;
    }
    __syncthreads();
    const float S = ssum[0] + ssum[1];

    if (tid < NBINS) {
        const float cnt = raw / S;
        out[tid] = cnt;                                // count
        const float b0 = bins[tid], b1 = bins[tid + 1];
        const float R  = bins[NBINS];                  // R_END = 7.5
        // rdf = cnt / (vol_bin / V) = cnt * R^3 / (b1^3 - b0^3)  (4pi/3 cancels)
        out[201 + tid] = cnt * (R * R * R) / (b1 * b1 * b1 - b0 * b0 * b0);
    }
    if (tid < NBINS + 1) {
        out[100 + tid] = bins[tid];                    // bins passthrough
    }
}

extern "C" void kernel_launch(void* const* d_in, const int* in_sizes, int n_in,
                              void* d_out, int out_size, void* d_ws, size_t ws_size,
                              hipStream_t stream) {
    const float* xyz     = (const float*)d_in[0];
    const float* cell    = (const float*)d_in[1];
    const float* bins    = (const float*)d_in[2];
    const float* offsets = (const float*)d_in[3];
    float* out = (float*)d_out;

    float*    acc    = (float*)d_ws;   // STRIPES*NBINS floats
    unsigned* ticket = (unsigned*)((char*)d_ws + STRIPES * NBINS * sizeof(float));

    // zero acc + ticket each call (graph-capture legal async memset)
    hipMemsetAsync(d_ws, 0, STRIPES * NBINS * sizeof(float) + sizeof(unsigned),
                   stream);
    rdf_fused<<<NBLOCKS, 512, 0, stream>>>(xyz, cell, offsets, bins, out,
                                           acc, ticket);
}

// Round 8
// 22.138 us; speedup vs baseline: 4.7782x; 1.1137x over previous
//
#include <hip/hip_runtime.h>
#include <hip/hip_bf16.h>

// RDF with minimum-image PBC + Gaussian smearing, N=2048 atoms, 100 bins.
//
// Round-8: back to TWO dispatches, zero cross-block sync machinery.
// Round 7's single-dispatch fusion lost to the two-kernel structure: the
// ticket (512 serialized same-address RMWs, on the critical path), the
// global atomic publish, and the RMW-read tail cost ~10us against a ~4us
// dispatch saving. Here: no ticket, no global atomics, no memset node —
// blocks plain-store their 100-bin partial (transposed [bin][block],
// fully overwritten every call -> deterministic, capture-safe).
//
// Hot-loop cost is LDS-atomic RMW serialization (diagnosed from round 2:
// 23M LDS atomics <-> 65us at 10% VALUBusy). Mitigation: FOUR private
// fine-histogram copies (one per 128-thread wave-pair, 28KB LDS) -> ~4x
// less same-address/bank contention; copies merged before the conv.
//
// Kernel 1 (rdf_pairs): 512 blocks x 512 threads; block owns 4 rows of
// the cyclic upper-triangle enumeration (j=(i+1+t) mod N, t in [0,1024);
// one predicate dedups the d==N/2 diagonal; the x2 pair weight cancels in
// normalization). i is wave-uniform -> scalar i-loads; j-loads are
// coalesced dwordx3, L1-resident (xyz=24KB). ONE LDS atomicAdd(1.0f) per
// pair into a fine histogram (17 sub-bins/bin; integer counts in f32 ->
// exact, order-independent). Epilogue: merge 4 copies, convolve with a
// 103-tap Gaussian (stride 17 coprime with 32 banks -> conflict-free).
// Pairs with dist < 8 bin-units (~200 device-wide) take an exact
// direct-smear path into bins 0..11 (tiny shell volumes amplify
// quantization error there).
//
// Kernel 2 (rdf_finalize): 1 block x 1024 threads; 8 chunks x 128 bins
// float4 reduce of partials[100][512], normalize, write
// d_out = [count(100) | bins(101) | rdf(100)].

#define N_ATOMS 2048
#define HALF    1024
#define NBINS   100
#define S_FINE  17          // fine sub-bins per coarse bin (coprime with 32)
#define FBINS   1744        // > 102.5 * 17 = 1742.5
#define NCOPY   4           // private fine-histogram copies (per wave-pair)
#define TAPS    103         // 2*3*17 + 1  (window +-3 bin widths)
#define NDIR    12          // exact direct-path coarse bins 0..11
#define TLOW    8.0f        // bin-units: below this, take the exact path
#define NBLOCKS 512
#define ROWS_PB 4           // N_ATOMS / NBLOCKS

__global__ __launch_bounds__(512) void rdf_pairs(
    const float* __restrict__ xyz,
    const float* __restrict__ cell,
    const float* __restrict__ offsets,
    float* __restrict__ partials)
{
    __shared__ float fine[NCOPY][FBINS];   // private fine histograms
    __shared__ float wtab[TAPS];           // Gaussian taps
    __shared__ float conv[NBINS][4];       // conv partials
    __shared__ float cd[16];               // exact direct-path coarse bins

    const int tid = threadIdx.x;

    for (int a = tid; a < NCOPY * FBINS; a += 512)
        (&fine[0][0])[a] = 0.0f;
    if (tid < 16)   cd[tid] = 0.0f;
    if (tid < TAPS) {
        const float u = ((float)tid - 50.5f) * (1.0f / (float)S_FINE);
        wtab[tid] = __expf(-0.5f * u * u);
    }
    __syncthreads();

    const float cx = cell[0], cy = cell[1], cz = cell[2];
    const float hcx = 0.5f * cx, hcy = 0.5f * cy, hcz = 0.5f * cz;

    const float width = offsets[1] - offsets[0];   // 7.5/99
    const float invw  = 1.0f / width;
    // beyond 102.5 bin-units no bin k<=99 lies within the +-3w window
    const float cutd   = 102.5f * width;           // 7.765 < CUTOFF_B = 8.0
    const float cut2   = cutd * cutd;

    float* const myfine = fine[tid >> 7];          // one copy per wave-pair

    // ---- main loop: 4 rows per block, i wave-uniform ----
    const int row0 = blockIdx.x << 2;
    #pragma unroll
    for (int r = 0; r < ROWS_PB; ++r) {
        const int i = row0 + r;
        const float xi = xyz[3 * i + 0];           // uniform -> scalar loads
        const float yi = xyz[3 * i + 1];
        const float zi = xyz[3 * i + 2];
        #pragma unroll
        for (int it = 0; it < HALF / 512; ++it) {
            const int th = tid + it * 512;
            if (th == HALF - 1 && i >= HALF) continue;   // dedup N/2 diagonal
            const int j = (i + 1 + th) & (N_ATOMS - 1);

            float dx = xyz[3 * j + 0] - xi;        // coalesced dwordx3
            float dy = xyz[3 * j + 1] - yi;
            float dz = xyz[3 * j + 2] - zi;
            // minimum-image wrap (matches reference shift semantics)
            dx += (dx >= hcx) ? -cx : ((dx < -hcx) ? cx : 0.0f);
            dy += (dy >= hcy) ? -cy : ((dy < -hcy) ? cy : 0.0f);
            dz += (dz >= hcz) ? -cz : ((dz < -hcz) ? cz : 0.0f);

            const float dsq = dx * dx + dy * dy + dz * dz;
            if (dsq < cut2 && dsq != 0.0f) {
                const float tu = sqrtf(dsq) * invw;    // dist in bin units
                if (tu >= TLOW) {
                    // ONE LDS atomic/pair into this wave-pair's copy
                    atomicAdd(&myfine[(int)(tu * (float)S_FINE)], 1.0f);
                } else {
                    // exact path for low bins (~200 pairs device-wide)
                    int khi = (int)tu + 4; if (khi > NDIR - 1) khi = NDIR - 1;
                    for (int k = 0; k <= khi; ++k) {
                        const float e = tu - (float)k;
                        atomicAdd(&cd[k], __expf(-0.5f * e * e));
                    }
                }
            }
        }
    }

    __syncthreads();

    // merge the 4 copies into copy 0 (stride-1, conflict-free)
    for (int a = tid; a < FBINS; a += 512)
        fine[0][a] += fine[1][a] + fine[2][a] + fine[3][a];
    __syncthreads();

    // coarse[k] = sum_d wtab[d+51] * fine[17k+d], d in [-51,51]
    // 400 threads: k = t>>2, chunk c = t&3 (26/26/26/25 taps); stride-17
    // fine reads are bank-conflict free (gcd(17,32)=1)
    if (tid < 400) {
        const int k = tid >> 2;
        const int c = tid & 3;
        const int m0 = c * 26;
        const int mcnt = (c == 3) ? 25 : 26;
        float s = 0.0f;
        for (int mm = 0; mm < mcnt; ++mm) {
            const int m = m0 + mm;
            const int f = S_FINE * k + m - 51;     // max 17*99+51 = 1734
            if (f >= 0) s += wtab[m] * fine[0][f];
        }
        conv[k][c] = s;
    }
    __syncthreads();

    if (tid < NBINS) {
        float raw = conv[tid][0] + conv[tid][1] + conv[tid][2] + conv[tid][3];
        if (tid < NDIR) raw += cd[tid];
        partials[tid * NBLOCKS + blockIdx.x] = raw;    // transposed, plain store
    }
}

__global__ __launch_bounds__(1024) void rdf_finalize(
    const float* __restrict__ partials,
    const float* __restrict__ bins,
    float* __restrict__ out)
{
    __shared__ float red[128][8];
    __shared__ float raw[NBINS];
    __shared__ float ssum[2];

    const int t = threadIdx.x;
    const int c = t & 7;        // chunk 0..7
    const int b = t >> 3;       // bin 0..127

    if (b < NBINS) {
        const int chunk = NBLOCKS / 8;                 // 64 floats
        const float4* src = (const float4*)(partials + b * NBLOCKS + c * chunk);
        float s0 = 0.0f, s1 = 0.0f;
        #pragma unroll
        for (int q = 0; q < chunk / 4; q += 2) {       // 16 float4, 2-way ILP
            const float4 v0 = src[q];
            const float4 v1 = src[q + 1];
            s0 += v0.x + v0.y + v0.z + v0.w;
            s1 += v1.x + v1.y + v1.z + v1.w;
        }
        red[b][c] = s0 + s1;
    }
    __syncthreads();

    if (t < NBINS) {
        float s = 0.0f;
        #pragma unroll
        for (int cc = 0; cc < 8; ++cc) s += red[t][cc];
        raw[t] = s;
    }
    __syncthreads();

    if (t < 128) {
        float v = (t < NBINS) ? raw[t] : 0.0f;
        #pragma unroll
        for (int o = 32; o > 0; o >>= 1) v += __shfl_down(v, o);
        if ((t & 63) == 0) ssum[t >> 6] = v;
    }
    __syncthreads();
    const float S = ssum[0] + ssum[1];

    if (t < NBINS) {
        const float cnt = raw[t] / S;
        out[t] = cnt;                                  // count
        const float b0 = bins[t], b1 = bins[t + 1];
        const float R  = bins[NBINS];                  // R_END = 7.5
        // rdf = cnt / (vol_bin / V) = cnt * R^3 / (b1^3 - b0^3)  (4pi/3 cancels)
        out[201 + t] = cnt * (R * R * R) / (b1 * b1 * b1 - b0 * b0 * b0);
    }
    if (t < NBINS + 1) {
        out[100 + t] = bins[t];                        // bins passthrough
    }
}

extern "C" void kernel_launch(void* const* d_in, const int* in_sizes, int n_in,
                              void* d_out, int out_size, void* d_ws, size_t ws_size,
                              hipStream_t stream) {
    const float* xyz     = (const float*)d_in[0];
    const float* cell    = (const float*)d_in[1];
    const float* bins    = (const float*)d_in[2];
    const float* offsets = (const float*)d_in[3];
    float* out      = (float*)d_out;
    float* partials = (float*)d_ws;    // NBINS * NBLOCKS floats, overwritten

    rdf_pairs<<<NBLOCKS, 512, 0, stream>>>(xyz, cell, offsets, partials);
    rdf_finalize<<<1, 1024, 0, stream>>>(partials, bins, out);
}